// Round 3
// baseline (45.934 us; speedup 1.0000x reference)
//
#include <hip/hip_runtime.h>
#include <hip/hip_fp16.h>

#define B_  8
#define C_  256
#define H_  64
#define W_  64
#define G_  4
#define CG_ 64
#define K_  9
#define HW_ (H_ * W_)  // 4096

// ---------------------------------------------------------------------------
// Kernel 1: NCHW fp32 -> group-major NHWC fp16  [B,C,HW] -> [B,G,HW,CG]
// 64ch (== one group) x 64px tiles; packed half2 in LDS; 128B store segments.
// ---------------------------------------------------------------------------
__global__ __launch_bounds__(256) void to_ghwc_f16(const float* __restrict__ in,
                                                   __half* __restrict__ out) {
  __shared__ unsigned int tile[32][65];  // [channel-pair][pixel]
  const int b  = blockIdx.z;
  const int p0 = blockIdx.x * 64;
  const int g  = blockIdx.y;             // C/64 == G
  const int tid = threadIdx.x;
  const float* src = in + (size_t)b * C_ * HW_ + (size_t)g * CG_ * HW_;
  __half* dst = out + ((size_t)(b * G_ + g) * HW_) * CG_;

  const int px  = tid & 63;
  const int cp0 = tid >> 6;  // 0..3
#pragma unroll
  for (int i = 0; i < 8; ++i) {
    const int cp = cp0 + i * 4;  // 0..31
    const int c  = cp * 2;
    const float v0 = src[(size_t)c * HW_ + p0 + px];
    const float v1 = src[(size_t)(c + 1) * HW_ + p0 + px];
    const unsigned int lo = (unsigned int)__half_as_ushort(__float2half(v0));
    const unsigned int hi = (unsigned int)__half_as_ushort(__float2half(v1));
    tile[cp][px] = lo | (hi << 16);
  }
  __syncthreads();

  const int cpair = tid & 31;  // 32 lanes x 4B = 128B = one pixel-group row
  const int pr0   = tid >> 5;  // 8 pixel rows per pass
#pragma unroll
  for (int i = 0; i < 8; ++i) {
    const int p = pr0 + i * 8;
    *(unsigned int*)(dst + (size_t)(p0 + p) * CG_ + 2 * cpair) = tile[cpair][p];
  }
}

// ---------------------------------------------------------------------------
// Kernel 2: deformable sampling from [B,G,HW,CG] fp16.
//   block = (ho, b, g): 256 threads = 8 channel-octets x 32 wi; each thread
//   owns pixels wo=wi and wo=wi+32  ->  8 independent 16B gathers in flight.
//   phase 1: 576 (pixel,tap) params (byte corner offsets + masked weights)
//   phase 2: gather + fp32 accumulate (v_fma_mix)
//   phase 3: LDS re-union'd as 64x65 staging tile; 256B coalesced stores.
// ---------------------------------------------------------------------------
union DeformSM {
  struct { int4 o[576]; float4 w[576]; } p;  // 18432 B
  float ot[64][65];                          // 16640 B
};

__global__ __launch_bounds__(256) void deform_g16(const __half* __restrict__ x,
                                                  const float* __restrict__ off,
                                                  const float* __restrict__ msk,
                                                  float* __restrict__ out) {
  __shared__ DeformSM sm;

  const int ho  = blockIdx.x;        // 0..63
  const int b   = blockIdx.y >> 2;   // 0..7
  const int g   = blockIdx.y & 3;    // 0..3
  const int tid = threadIdx.x;

  // ---- phase 1: params for 64 pixels x 9 taps (e = k*64 + px: coalesced) ----
  for (int e = tid; e < 576; e += 256) {
    const int px = e & 63;   // == wo
    const int k  = e >> 6;
    const int ky = k / 3, kx = k - ky * 3;
    const int och = (g * K_ + k) * 2;
    const size_t ob = ((size_t)(b * (2 * G_ * K_) + och) * HW_) + ho * W_ + px;
    const float dy = off[ob];
    const float dx = off[ob + HW_];
    const float m  = msk[((size_t)(b * (G_ * K_) + g * K_ + k) * HW_) + ho * W_ + px];

    const float py = (float)(ho - 1 + ky) + dy;
    const float pxx = (float)(px - 1 + kx) + dx;
    const float fy = floorf(py), fx = floorf(pxx);
    const int y0 = (int)fy, x0 = (int)fx;
    const int y1 = y0 + 1,  x1 = x0 + 1;
    const float ly = py - fy, lx = pxx - fx;

    const bool vy0 = ((unsigned)y0 < (unsigned)H_), vy1 = ((unsigned)y1 < (unsigned)H_);
    const bool vx0 = ((unsigned)x0 < (unsigned)W_), vx1 = ((unsigned)x1 < (unsigned)W_);
    const float wy0 = (1.f - ly) * m, wy1 = ly * m;

    float4 w;
    w.x = (vy0 && vx0) ? wy0 * (1.f - lx) : 0.f;
    w.y = (vy0 && vx1) ? wy0 * lx         : 0.f;
    w.z = (vy1 && vx0) ? wy1 * (1.f - lx) : 0.f;
    w.w = (vy1 && vx1) ? wy1 * lx         : 0.f;

    const int y0c = min(max(y0, 0), H_ - 1), y1c = min(max(y1, 0), H_ - 1);
    const int x0c = min(max(x0, 0), W_ - 1), x1c = min(max(x1, 0), W_ - 1);

    int4 o;  // BYTE offsets into the group slab (pix * CG * 2 = pix << 7)
    o.x = (y0c * W_ + x0c) << 7;
    o.y = (y0c * W_ + x1c) << 7;
    o.z = (y1c * W_ + x0c) << 7;
    o.w = (y1c * W_ + x1c) << 7;
    sm.p.o[e] = o;
    sm.p.w[e] = w;
  }
  __syncthreads();

  // ---- phase 2: 2 pixels x 8 channels per thread ----
  const int ci = tid & 7;    // channel octet
  const int wi = tid >> 3;   // 0..31; pixels wi and wi+32
  const char* xb = (const char*)x + (size_t)(b * G_ + g) * HW_ * CG_ * 2 + ci * 16;

  float a0[8] = {0.f, 0.f, 0.f, 0.f, 0.f, 0.f, 0.f, 0.f};
  float a1[8] = {0.f, 0.f, 0.f, 0.f, 0.f, 0.f, 0.f, 0.f};

#pragma unroll
  for (int k = 0; k < 9; ++k) {
    const int4   oA = sm.p.o[k * 64 + wi];
    const float4 wA = sm.p.w[k * 64 + wi];
    const int4   oB = sm.p.o[k * 64 + wi + 32];
    const float4 wB = sm.p.w[k * 64 + wi + 32];

    const float4 rA0 = *(const float4*)(xb + oA.x);
    const float4 rA1 = *(const float4*)(xb + oA.y);
    const float4 rA2 = *(const float4*)(xb + oA.z);
    const float4 rA3 = *(const float4*)(xb + oA.w);
    const float4 rB0 = *(const float4*)(xb + oB.x);
    const float4 rB1 = *(const float4*)(xb + oB.y);
    const float4 rB2 = *(const float4*)(xb + oB.z);
    const float4 rB3 = *(const float4*)(xb + oB.w);

    const __half* hA0 = (const __half*)&rA0;
    const __half* hA1 = (const __half*)&rA1;
    const __half* hA2 = (const __half*)&rA2;
    const __half* hA3 = (const __half*)&rA3;
    const __half* hB0 = (const __half*)&rB0;
    const __half* hB1 = (const __half*)&rB1;
    const __half* hB2 = (const __half*)&rB2;
    const __half* hB3 = (const __half*)&rB3;
#pragma unroll
    for (int j = 0; j < 8; ++j) {
      float s0 = a0[j];
      s0 = fmaf(wA.x, __half2float(hA0[j]), s0);
      s0 = fmaf(wA.y, __half2float(hA1[j]), s0);
      s0 = fmaf(wA.z, __half2float(hA2[j]), s0);
      s0 = fmaf(wA.w, __half2float(hA3[j]), s0);
      a0[j] = s0;
      float s1 = a1[j];
      s1 = fmaf(wB.x, __half2float(hB0[j]), s1);
      s1 = fmaf(wB.y, __half2float(hB1[j]), s1);
      s1 = fmaf(wB.z, __half2float(hB2[j]), s1);
      s1 = fmaf(wB.w, __half2float(hB3[j]), s1);
      a1[j] = s1;
    }
  }

  __syncthreads();  // params dead; reuse LDS as staging tile
#pragma unroll
  for (int j = 0; j < 8; ++j) {
    sm.ot[ci * 8 + j][wi]      = a0[j];
    sm.ot[ci * 8 + j][wi + 32] = a1[j];
  }
  __syncthreads();

  // ---- phase 3: coalesced store, 64 lanes x 4B = 256B per row ----
  float* ob = out + ((size_t)(b * C_ + g * CG_)) * HW_ + ho * W_;
  const int lane = tid & 63;
  const int r0   = tid >> 6;  // 0..3
#pragma unroll
  for (int q = 0; q < 16; ++q) {
    const int c = q * 4 + r0;
    ob[(size_t)c * HW_ + lane] = sm.ot[c][lane];
  }
}

// ---------------------------------------------------------------------------
// Fallback (no workspace): fp32 NCHW gathers, 4 ch/thread.
// ---------------------------------------------------------------------------
__global__ __launch_bounds__(256) void deform_f32_nchw(const float* __restrict__ x,
                                                       const float* __restrict__ off,
                                                       const float* __restrict__ msk,
                                                       float* __restrict__ out) {
  __shared__ int4   s_o[144];
  __shared__ float4 s_w[144];
  const int woq = blockIdx.x;
  const int ho  = blockIdx.y;
  const int b   = blockIdx.z >> 2;
  const int g   = blockIdx.z & 3;
  const int tid = threadIdx.x;

  if (tid < 144) {
    const int wi = tid / 9, k = tid - wi * 9;
    const int wo = woq * 16 + wi;
    const int ky = k / 3, kx = k - ky * 3;
    const int och = (g * K_ + k) * 2;
    const size_t ob = ((size_t)(b * (2 * G_ * K_) + och) * H_ + ho) * W_ + wo;
    const float dy = off[ob];
    const float dx = off[ob + HW_];
    const float m  = msk[((size_t)(b * (G_ * K_) + g * K_ + k) * H_ + ho) * W_ + wo];
    const float py = (float)(ho - 1 + ky) + dy;
    const float px = (float)(wo - 1 + kx) + dx;
    const float fy = floorf(py), fx = floorf(px);
    const int y0 = (int)fy, x0 = (int)fx;
    const int y1 = y0 + 1,  x1 = x0 + 1;
    const float ly = py - fy, lx = px - fx;
    const bool vy0 = ((unsigned)y0 < (unsigned)H_), vy1 = ((unsigned)y1 < (unsigned)H_);
    const bool vx0 = ((unsigned)x0 < (unsigned)W_), vx1 = ((unsigned)x1 < (unsigned)W_);
    const float wy0 = (1.f - ly) * m, wy1 = ly * m;
    float4 w;
    w.x = (vy0 && vx0) ? wy0 * (1.f - lx) : 0.f;
    w.y = (vy0 && vx1) ? wy0 * lx         : 0.f;
    w.z = (vy1 && vx0) ? wy1 * (1.f - lx) : 0.f;
    w.w = (vy1 && vx1) ? wy1 * lx         : 0.f;
    const int y0c = min(max(y0, 0), H_ - 1), y1c = min(max(y1, 0), H_ - 1);
    const int x0c = min(max(x0, 0), W_ - 1), x1c = min(max(x1, 0), W_ - 1);
    s_o[tid] = make_int4(y0c * W_ + x0c, y0c * W_ + x1c, y1c * W_ + x0c, y1c * W_ + x1c);
    s_w[tid] = w;
  }
  __syncthreads();

  const int ci = tid & 15, wi = tid >> 4;
  const float* xb = x + (size_t)(b * C_ + g * CG_ + ci * 4) * HW_;
  float a0 = 0.f, a1 = 0.f, a2 = 0.f, a3 = 0.f;
#pragma unroll
  for (int k = 0; k < 9; ++k) {
    const int e = wi * 9 + k;
    const int4   o = s_o[e];
    const float4 w = s_w[e];
    a0 += w.x * xb[o.x] + w.y * xb[o.y] + w.z * xb[o.z] + w.w * xb[o.w];
    const float* x1p = xb + HW_;
    a1 += w.x * x1p[o.x] + w.y * x1p[o.y] + w.z * x1p[o.z] + w.w * x1p[o.w];
    const float* x2p = xb + 2 * HW_;
    a2 += w.x * x2p[o.x] + w.y * x2p[o.y] + w.z * x2p[o.z] + w.w * x2p[o.w];
    const float* x3p = xb + 3 * HW_;
    a3 += w.x * x3p[o.x] + w.y * x3p[o.y] + w.z * x3p[o.z] + w.w * x3p[o.w];
  }
  float* ob = out + ((size_t)(b * C_ + g * CG_ + ci * 4)) * HW_ + ho * W_ + woq * 16 + wi;
  ob[0] = a0; ob[HW_] = a1; ob[2 * HW_] = a2; ob[3 * HW_] = a3;
}

// ---------------------------------------------------------------------------
extern "C" void kernel_launch(void* const* d_in, const int* in_sizes, int n_in,
                              void* d_out, int out_size, void* d_ws, size_t ws_size,
                              hipStream_t stream) {
  const float* inp = (const float*)d_in[0];
  const float* off = (const float*)d_in[1];
  const float* msk = (const float*)d_in[2];
  float* out = (float*)d_out;

  const size_t need = (size_t)B_ * C_ * HW_ * sizeof(__half);  // 16.8 MB
  if (ws_size >= need) {
    __half* xt = (__half*)d_ws;
    to_ghwc_f16<<<dim3(HW_ / 64, G_, B_), 256, 0, stream>>>(inp, xt);
    deform_g16<<<dim3(H_, B_ * G_), 256, 0, stream>>>(xt, off, msk, out);
  } else {
    deform_f32_nchw<<<dim3(4, H_, B_ * G_), 256, 0, stream>>>(inp, off, msk, out);
  }
}